// Round 4
// baseline (56.571 us; speedup 1.0000x reference)
//
#include <hip/hip_runtime.h>
#include <math.h>

// Problem constants (from reference)
constexpr int kC   = 3;
constexpr int kTIn = 2048;
constexpr int kR   = 64;
constexpr int kTB  = 128;
constexpr float kAlpha = 10.0f;
constexpr float kLog2e = 1.44269504088896f;

constexpr int kK     = 4;                 // samples per wave (pipeline depth)
constexpr int kLoads = kC * kTIn / 4 / 64; // 24 float4 loads per lane per sample

#ifndef __has_builtin
#define __has_builtin(x) 0
#endif

static __device__ __forceinline__ float fast_rcp(float x) {
#if __has_builtin(__builtin_amdgcn_rcpf)
    return __builtin_amdgcn_rcpf(x);
#else
    return 1.0f / x;
#endif
}

static __device__ __forceinline__ float fast_exp2(float x) {
#if __has_builtin(__builtin_amdgcn_exp2f)
    return __builtin_amdgcn_exp2f(x);
#else
    return __builtin_exp2f(x);
#endif
}

static __device__ __forceinline__ void sched_fence() {
#if __has_builtin(__builtin_amdgcn_sched_barrier)
    __builtin_amdgcn_sched_barrier(0);
#endif
}

// ---------------------------------------------------------------------------
// Per-resonator transcendental params, once (libm accuracy).
// ws: [4][kR] = freq, decay, thr, thrE (= ALPHA*log2e*thr)
// ---------------------------------------------------------------------------
__global__ void param_kernel(const float* __restrict__ freq_raw,
                             const float* __restrict__ q_raw,
                             const float* __restrict__ thr_raw,
                             float* __restrict__ pp)
{
    const int r = threadIdx.x;
    if (r >= kR) return;
    const float freq  = 0.03f + 0.17f / (1.0f + expf(-freq_raw[r]));
    const float qf    = 1.5f + log1pf(expf(q_raw[r]));
    const float decay = expf(-1.0f / qf);
    const float thr   = 0.35f + 0.75f / (1.0f + expf(-thr_raw[r]));
    pp[0 * kR + r] = freq;
    pp[1 * kR + r] = decay;
    pp[2 * kR + r] = thr;
    pp[3 * kR + r] = thr * (kAlpha * kLog2e);
}

// ---------------------------------------------------------------------------
// Persistent-wave pipeline: each wave owns K samples, no barriers anywhere.
//   iter k: pool R (regs) -> sp (private LDS) + wave max-abs;
//           issue next sample's 24 float4 loads into R (pinned by sched fence);
//           128-step scan (loads drain underneath); store.
// ---------------------------------------------------------------------------
__global__ __launch_bounds__(256, 2)
void fused_encoder_kernel(const float* __restrict__ traces,
                          const float* __restrict__ drive_w,
                          const float* __restrict__ drive_b,
                          const float* __restrict__ pp,
                          float* __restrict__ out,
                          int W, int K)
{
    __shared__ float sp_all[4][kTB * 4];     // per-wave private 2 KB, no barriers
    const int tid  = threadIdx.x;
    const int wave = tid >> 6;
    const int lane = tid & 63;
    float* sp = sp_all[wave];
    const int gw = blockIdx.x * 4 + wave;    // global wave id in [0, W)

    // per-lane resonator params (hoisted out of the sample loop)
    const int r = lane;
    const float w0   = drive_w[r * kC + 0];
    const float w1   = drive_w[r * kC + 1];
    const float w2   = drive_w[r * kC + 2];
    const float bias = drive_b[r];
    const float freq  = pp[0 * kR + r];
    const float decay = pp[1 * kR + r];
    const float thr   = pp[2 * kR + r];
    const float thrE  = pp[3 * kR + r];
    const float expScale = kAlpha * kLog2e;

    const float4* tr4 = reinterpret_cast<const float4*>(traces);

    float4 R[kLoads];
    {   // prologue: prefetch sample for k=0
        const float4* src = tr4 + (long long)gw * (kC * kTIn / 4) + lane;
        #pragma unroll
        for (int j = 0; j < kLoads; ++j) R[j] = src[j * 64];
    }

    for (int k = 0; k < K; ++k) {
        const long long b = (long long)k * W + gw;

        // ---- pool R -> sp (t-major {c0,c1,c2,pad}) + wave max-abs ----
        // float4 f = j*64+lane covers quarter of window w = j*16 + (lane>>2)
        float m = 0.0f;
        #pragma unroll
        for (int j = 0; j < kLoads; ++j) {
            float4 v = R[j];
            float s = (v.x + v.y) + (v.z + v.w);
            s += __shfl_xor(s, 1, 64);
            s += __shfl_xor(s, 2, 64);       // window sum in all 4 quad lanes
            m = fmaxf(m, fabsf(s));
            if ((lane & 3) == 0) {
                int w = j * 16 + (lane >> 2);
                sp[(w & 127) * 4 + (w >> 7)] = s;   // 2-way bank alias: free
            }
        }
        #pragma unroll
        for (int off = 32; off >= 4; off >>= 1)      // quads already uniform
            m = fmaxf(m, __shfl_xor(m, off, 64));

        const float inv = fast_rcp(fmaxf(m * (1.0f / 16.0f), 1.0f)) * (1.0f / 16.0f);
        const float v0 = w0 * inv, v1 = w1 * inv, v2 = w2 * inv;

        // ---- issue next sample's loads (stay in flight across the scan) ----
        if (k + 1 < K) {
            const float4* src = tr4 + ((long long)(k + 1) * W + gw) * (kC * kTIn / 4) + lane;
            #pragma unroll
            for (int j = 0; j < kLoads; ++j) R[j] = src[j * 64];
        }
        sched_fence();   // pin load issue BEFORE the scan

        // ---- 128-step resonator scan (broadcast ds_read_b128 per step) ----
        const float4* pt = reinterpret_cast<const float4*>(sp);
        float state = 0.0f, vel = 0.0f, acc = 0.0f;
        #pragma unroll 8
        for (int t = 0; t < kTB; ++t) {
            float4 p = pt[t];
            float cur = fmaf(p.x, v0, bias);
            cur = fmaf(p.y, v1, cur);
            cur = fmaf(p.z, v2, cur);
            vel = fmaf(decay, vel, cur);
            vel = fmaf(-freq, state, vel);
            state = fmaf(freq, vel, state);
            float e = fast_exp2(fmaf(-expScale, state, thrE));
            float spike = fast_rcp(1.0f + e);
            state = fmaf(-spike, thr, state);
            acc += spike;
        }

        out[b * kR + r] = acc * (1.0f / kTB);
    }
}

extern "C" void kernel_launch(void* const* d_in, const int* in_sizes, int n_in,
                              void* d_out, int out_size, void* d_ws, size_t ws_size,
                              hipStream_t stream)
{
    const float* traces   = (const float*)d_in[0];
    const float* drive_w  = (const float*)d_in[1];
    const float* drive_b  = (const float*)d_in[2];
    const float* freq_raw = (const float*)d_in[3];
    const float* q_raw    = (const float*)d_in[4];
    const float* thr_raw  = (const float*)d_in[5];
    float* out = (float*)d_out;
    float* pp  = (float*)d_ws;

    const int totalB = in_sizes[0] / (kC * kTIn);   // 8192
    const int W = totalB / kK;                      // 2048 waves
    const int grid = W / 4;                         // 512 blocks of 4 waves

    param_kernel<<<1, 64, 0, stream>>>(freq_raw, q_raw, thr_raw, pp);
    fused_encoder_kernel<<<grid, 256, 0, stream>>>(traces, drive_w, drive_b, pp, out, W, kK);
}